// Round 1
// 356.198 us; speedup vs baseline: 1.0046x; 1.0046x over previous
//
#include <hip/hip_runtime.h>
#include <math.h>

#define ROWS 65536
#define COLS 1000
#define STRIDE 1001            // floats per row
#define ROWBYTES 4004          // STRIDE * 4 bytes
#define K1_BLOCKS 2048
#define WAVES_PER_BLOCK 4
#define NLOGEPS 13.815510558f  // -logf(1e-6f)

// One wave (64 lanes) per row. Row = 1000 logits + 1 "extra".
// Loads: round row base DOWN to 16B -> all loads are aligned dwordx4.
//   lane holds float4 words {lane + 64k}, k=0..3 (word idx <= 250 kept in-buffer;
//   last row has shift=3 so max byte read == buffer end exactly).
// Math: log(sigmoid(extra-l)) = -log(1 + exp(l-extra)), and
//   exp(l-extra) = exp(l-m) * exp(m-extra) = e_k * K  (K wave-uniform)
//   -> second exp pass and rcp eliminated; 1/se factored out of inner loop.
__global__ __launch_bounds__(256) void row_loss_kernel(
    const float* __restrict__ in, float* __restrict__ partial) {
    const int lane  = threadIdx.x & 63;
    const int wave  = threadIdx.x >> 6;
    const int gwave = blockIdx.x * WAVES_PER_BLOCK + wave;
    const int nwaves = gridDim.x * WAVES_PER_BLOCK;
    const char* inb = (const char*)in;

    float wsum = 0.0f;
    for (int row = gwave; row < ROWS; row += nwaves) {
        const size_t base  = (size_t)row * ROWBYTES;
        const size_t abase = base & ~(size_t)15;
        const int shift    = (int)((base & 15) >> 2);       // = row & 3
        const float4* rp4  = (const float4*)(inb + abase);
        const float*  rp   = (const float*)(inb + base);

        // ---- aligned vector load: 4x dwordx4 per lane (words lane+64k) ----
        float4 vv[4];
        vv[0] = rp4[lane];
        vv[1] = rp4[lane + 64];
        vv[2] = rp4[lane + 128];
        vv[3] = make_float4(0.f, 0.f, 0.f, 0.f);
        if (lane <= 58) vv[3] = rp4[lane + 192];            // word idx <= 250
        float extra = rp[COLS];                             // wave-uniform addr

        float l[16];
        #pragma unroll
        for (int k = 0; k < 4; ++k) {
            l[4*k + 0] = vv[k].x;
            l[4*k + 1] = vv[k].y;
            l[4*k + 2] = vv[k].z;
            l[4*k + 3] = vv[k].w;
        }

        // Mask out-of-row elements ONCE: column c = 4*lane + 256*k + j - shift.
        // l = -inf  =>  exp(l-m) = 0  => contributes nothing downstream.
        const int cbase = 4 * lane - shift;
        #pragma unroll
        for (int k = 0; k < 4; ++k) {
            #pragma unroll
            for (int j = 0; j < 4; ++j) {
                int c = cbase + 256 * k + j;
                if ((unsigned)c >= (unsigned)COLS) l[4*k + j] = -INFINITY;
            }
        }

        // ---- row max (regs then 6-step butterfly) ----
        float m = l[0];
        #pragma unroll
        for (int k = 1; k < 16; ++k) m = fmaxf(m, l[k]);
        #pragma unroll
        for (int off = 32; off > 0; off >>= 1) m = fmaxf(m, __shfl_xor(m, off));

        // ---- e_k = exp(l - m), se = sum ----
        float e[16];
        float se = 0.0f;
        #pragma unroll
        for (int k = 0; k < 16; ++k) {
            float v = __expf(l[k] - m);     // -inf -> 0 for masked slots
            e[k] = v;
            se += v;
        }
        #pragma unroll
        for (int off = 32; off > 0; off >>= 1) se += __shfl_xor(se, off);

        // ---- sum_c e_c * log(1 + exp(l_c - extra)),  exp(l-extra) = e*K ----
        const float K = __expf(m - extra);  // wave-uniform
        float acc = 0.0f;
        #pragma unroll
        for (int k = 0; k < 16; ++k) {
            float u = fmaf(e[k], K, 1.0f);          // 1 + exp(l-extra), >= 1
            float lg = __logf(u);                   // >= 0
            if (u == INFINITY) lg = NLOGEPS;        // reference pc==0 -> EPS guard
            acc = fmaf(e[k], lg, acc);
        }
        #pragma unroll
        for (int off = 32; off > 0; off >>= 1) acc += __shfl_xor(acc, off);

        // t = sum_c p_c * log(sigmoid) = -acc / se
        wsum -= acc / se;   // one divide per row, wave-uniform
    }

    __shared__ float sdata[WAVES_PER_BLOCK];
    if (lane == 0) sdata[wave] = wsum;
    __syncthreads();
    if (threadIdx.x == 0) {
        float b = 0.0f;
        #pragma unroll
        for (int w = 0; w < WAVES_PER_BLOCK; ++w) b += sdata[w];
        partial[blockIdx.x] = b;
    }
}

__global__ __launch_bounds__(256) void final_reduce(
    const float* __restrict__ partial, float* __restrict__ out) {
    float s = 0.0f;
    for (int i = threadIdx.x; i < K1_BLOCKS; i += 256) s += partial[i];
    #pragma unroll
    for (int off = 32; off > 0; off >>= 1) s += __shfl_xor(s, off);
    __shared__ float sdata[4];
    const int lane = threadIdx.x & 63, wave = threadIdx.x >> 6;
    if (lane == 0) sdata[wave] = s;
    __syncthreads();
    if (threadIdx.x == 0) {
        float tot = sdata[0] + sdata[1] + sdata[2] + sdata[3];
        out[0] = -tot / (float)ROWS;
    }
}

extern "C" void kernel_launch(void* const* d_in, const int* in_sizes, int n_in,
                              void* d_out, int out_size, void* d_ws, size_t ws_size,
                              hipStream_t stream) {
    const float* in = (const float*)d_in[0];   // (65536, 1001) fp32
    // d_in[1] (target) is unused by the reference computation.
    float* partial = (float*)d_ws;             // K1_BLOCKS floats
    row_loss_kernel<<<K1_BLOCKS, 256, 0, stream>>>(in, partial);
    final_reduce<<<1, 256, 0, stream>>>(partial, (float*)d_out);
}